// Round 4
// baseline (309.411 us; speedup 1.0000x reference)
//
#include <hip/hip_runtime.h>
#include <math.h>

// Problem constants
#define B_  4
#define N_  170
#define T_  96
#define D_  256
#define H_  8
#define HD_ 32
#define R_  (B_*N_*T_)    // 65280 rows
#define G_  (B_*N_*H_)    // 5440 attention groups
#define GSZ (T_*HD_)      // 3072 elements per group per tensor
#define QSZ (R_*D_)       // 16,711,680 elements per q/k/v buffer (bf16)
#define WSZ (D_*D_)       // 65536 per weight matrix

typedef short  bf16x8 __attribute__((ext_vector_type(8)));
typedef float  f32x4  __attribute__((ext_vector_type(4)));
typedef unsigned int u32;

__device__ __forceinline__ ushort to_bf16(float x)
{
    uint u = __builtin_bit_cast(uint, x);
    u += 0x8000u;                      // round-half-up
    return (ushort)(u >> 16);
}

// split fp32 pair into packed bf16 hi (truncate; x-hi exact) and lo words
__device__ __forceinline__ void split2(float x0, float x1, uint& hi, uint& lo)
{
    uint u0 = __builtin_bit_cast(uint, x0);
    uint u1 = __builtin_bit_cast(uint, x1);
    hi = (u0 >> 16) | (u1 & 0xFFFF0000u);
    float h0 = __builtin_bit_cast(float, u0 & 0xFFFF0000u);
    float h1 = __builtin_bit_cast(float, u1 & 0xFFFF0000u);
    float l0 = x0 - h0, l1 = x1 - h1;
    uint v0 = __builtin_bit_cast(uint, l0);
    uint v1 = __builtin_bit_cast(uint, l1);
    lo = (v0 >> 16) | (v1 & 0xFFFF0000u);
}

__device__ __forceinline__ void split8(float4 a0, float4 a1, uint4& hi, uint4& lo)
{
    split2(a0.x, a0.y, hi.x, lo.x);
    split2(a0.z, a0.w, hi.y, lo.y);
    split2(a1.x, a1.y, hi.z, lo.z);
    split2(a1.z, a1.w, hi.w, lo.w);
}

// async global->LDS, 16B per lane; lds dest = wave-uniform base + lane*16 (HW)
__device__ __forceinline__ void async_load16(const void* g, void* l)
{
    __builtin_amdgcn_global_load_lds(
        (const u32 __attribute__((address_space(1)))*)g,
        (u32 __attribute__((address_space(3)))*)l,
        16, 0, 0);
}

// ---------------------------------------------------------------------------
// Kernel 0: one-time W split. W[col][k] fp32 -> hi/lo bf16 in chunked layout
// [k/8][col][8] per matrix (so a GEMM B-tile is contiguous 16B chunk runs).
// Wq gets 1/sqrt(32) folded in. mats: 0=Wq 1=Wk 2=Wv 3=Wo.
// ---------------------------------------------------------------------------
__global__ __launch_bounds__(256)
void splitw_kernel(const float* __restrict__ Wq, const float* __restrict__ Wk,
                   const float* __restrict__ Wv, const float* __restrict__ Wo,
                   ushort* __restrict__ whi, ushort* __restrict__ wlo)
{
    const int gid = blockIdx.x * 256 + threadIdx.x;   // 32768 chunks
    const int mat = gid >> 13;
    const int rem = gid & 8191;
    const int col = rem >> 5;
    const int kc  = rem & 31;
    const float* W = (mat == 0) ? Wq : (mat == 1) ? Wk : (mat == 2) ? Wv : Wo;
    const float s  = (mat == 0) ? 0.17677669529663687f : 1.0f;
    const float* p = W + (size_t)col * D_ + kc * 8;
    float4 a0 = *(const float4*)p;
    float4 a1 = *(const float4*)(p + 4);
    a0.x *= s; a0.y *= s; a0.z *= s; a0.w *= s;
    a1.x *= s; a1.y *= s; a1.z *= s; a1.w *= s;
    uint4 h, l;
    split8(a0, a1, h, l);
    const size_t off = (size_t)mat * WSZ + ((size_t)kc * 256 + col) * 8;
    *(uint4*)(whi + off) = h;
    *(uint4*)(wlo + off) = l;
}

// ---------------------------------------------------------------------------
// Kernel 1: fused Q/K/V projection, split-bf16 MFMA.
// A (X) staged via fp32 load + split; B (pre-split W) via global_load_lds.
// BM=128, BN=128, BK=32, 256 thr = 4 waves (2x2), 64x64 per wave.
// Grid (2, 510, 3): col tiles adjacent -> X row-panel L2 reuse.
// ---------------------------------------------------------------------------
__global__ __launch_bounds__(256)
void proj_kernel(const float* __restrict__ Xq, const float* __restrict__ Xk,
                 const float* __restrict__ Xv,
                 const ushort* __restrict__ whi, const ushort* __restrict__ wlo,
                 const float* __restrict__ bq, const float* __restrict__ bk,
                 const float* __restrict__ bv,
                 ushort* __restrict__ oq, ushort* __restrict__ ok_,
                 ushort* __restrict__ ov)
{
    const int z = blockIdx.z;
    const float* X    = (z == 0) ? Xq : (z == 1) ? Xk : Xv;
    const float* bias = (z == 0) ? bq : (z == 1) ? bk : bv;
    ushort*      out  = (z == 0) ? oq : (z == 1) ? ok_ : ov;
    const ushort* Bhg = whi + (size_t)z * WSZ;
    const ushort* Blg = wlo + (size_t)z * WSZ;

    const int tid  = threadIdx.x;
    const int col0 = blockIdx.x * 128;
    const int row0 = blockIdx.y * 128;
    const int lane = tid & 63;
    const int w    = tid >> 6;
    const int wr   = w >> 1;
    const int wc   = w & 1;
    const int lr   = lane & 15;
    const int kgl  = lane >> 4;

    // chunked planes [kg][idx][8] bf16, 16B per chunk, 2KB per plane
    __shared__ __align__(16) ushort Ah[4*128*8];
    __shared__ __align__(16) ushort Al[4*128*8];
    __shared__ __align__(16) ushort Bh[4*128*8];
    __shared__ __align__(16) ushort Bl[4*128*8];

    f32x4 acc[4][4];
    #pragma unroll
    for (int m = 0; m < 4; m++)
        #pragma unroll
        for (int n = 0; n < 4; n++) acc[m][n] = (f32x4)0.f;

    for (int k0 = 0; k0 < D_; k0 += 32) {
        // ---- B tile: global_load_lds, wave w owns plane kg = w (128 chunks, 2 issues each buf)
        {
            const int kg = w;
            const ushort* gh = Bhg + ((size_t)(k0/8 + kg) * 256 + col0) * 8;
            const ushort* gl = Blg + ((size_t)(k0/8 + kg) * 256 + col0) * 8;
            const uint off = (uint)__builtin_amdgcn_readfirstlane(kg * 2048);
            async_load16(gh + (size_t)lane * 8,        (char*)Bh + off);
            async_load16(gh + (size_t)(64 + lane) * 8, (char*)Bh + off + 1024);
            async_load16(gl + (size_t)lane * 8,        (char*)Bl + off);
            async_load16(gl + (size_t)(64 + lane) * 8, (char*)Bl + off + 1024);
        }
        // ---- A tile: fp32 load + split -> LDS (512 chunks, 2/thread)
        #pragma unroll
        for (int i = 0; i < 2; i++) {
            const int c  = tid + i * 256;
            const int kg = c >> 7;
            const int r  = c & 127;
            const float* pa = X + (size_t)(row0 + r) * D_ + k0 + kg * 8;
            float4 a0 = *(const float4*)pa;
            float4 a1 = *(const float4*)(pa + 4);
            uint4 h, l;
            split8(a0, a1, h, l);
            *(uint4*)&Ah[(kg*128 + r)*8] = h;
            *(uint4*)&Al[(kg*128 + r)*8] = l;
        }
        __syncthreads();   // drains vmcnt (gl_lds) + lgkmcnt

        bf16x8 ah[4], al[4], bh[4], bl[4];
        #pragma unroll
        for (int m = 0; m < 4; m++) {
            const int ra = wr*64 + m*16 + lr;
            ah[m] = *(const bf16x8*)&Ah[(kgl*128 + ra)*8];
            al[m] = *(const bf16x8*)&Al[(kgl*128 + ra)*8];
        }
        #pragma unroll
        for (int n = 0; n < 4; n++) {
            const int cb = wc*64 + n*16 + lr;
            bh[n] = *(const bf16x8*)&Bh[(kgl*128 + cb)*8];
            bl[n] = *(const bf16x8*)&Bl[(kgl*128 + cb)*8];
        }
        #pragma unroll
        for (int m = 0; m < 4; m++)
            #pragma unroll
            for (int n = 0; n < 4; n++) {
                acc[m][n] = __builtin_amdgcn_mfma_f32_16x16x32_bf16(ah[m], bl[n], acc[m][n], 0, 0, 0);
                acc[m][n] = __builtin_amdgcn_mfma_f32_16x16x32_bf16(al[m], bh[n], acc[m][n], 0, 0, 0);
                acc[m][n] = __builtin_amdgcn_mfma_f32_16x16x32_bf16(ah[m], bh[n], acc[m][n], 0, 0, 0);
            }
        __syncthreads();
    }

    // epilogue: + s*bias -> bf16, head-split store (W pre-scaled for z==0)
    const float sc = (z == 0) ? 0.17677669529663687f : 1.0f;
    if (z < 2) {
        #pragma unroll
        for (int n = 0; n < 4; n++) {
            const int gcol = col0 + wc*64 + n*16 + lr;
            const int h    = gcol >> 5;
            const int hd   = gcol & 31;
            const float bvs = bias[gcol] * sc;
            #pragma unroll
            for (int m = 0; m < 4; m++) {
                #pragma unroll
                for (int reg = 0; reg < 4; reg++) {
                    const int grow = row0 + wr*64 + m*16 + kgl*4 + reg;
                    const int bn = grow / T_;
                    const int t  = grow - bn * T_;
                    out[(size_t)((bn*H_ + h)*T_ + t)*HD_ + hd] = to_bf16(acc[m][n][reg] + bvs);
                }
            }
        }
    } else {
        // v: [g][hd][t], pack 4 consecutive t (reg dim) into ushort4
        #pragma unroll
        for (int n = 0; n < 4; n++) {
            const int gcol = col0 + wc*64 + n*16 + lr;
            const int h    = gcol >> 5;
            const int hd   = gcol & 31;
            const float bvs = bias[gcol];
            #pragma unroll
            for (int m = 0; m < 4; m++) {
                const int grow0 = row0 + wr*64 + m*16 + kgl*4;  // 4 | 96 -> one bn
                const int bn = grow0 / T_;
                const int t0 = grow0 - bn * T_;
                ushort4 pk;
                pk.x = to_bf16(acc[m][n][0] + bvs);
                pk.y = to_bf16(acc[m][n][1] + bvs);
                pk.z = to_bf16(acc[m][n][2] + bvs);
                pk.w = to_bf16(acc[m][n][3] + bvs);
                *(ushort4*)&out[(size_t)((bn*H_ + h)*HD_ + hd)*T_ + t0] = pk;
            }
        }
    }
}

// ---------------------------------------------------------------------------
// Kernel 2: MFMA attention, one block per (bn,h), 384 thr = 6 waves.
// Output O written as bf16 hi/lo (row-major [bn*96+t][h*32+hd]) for wo_kernel.
// ---------------------------------------------------------------------------
__global__ __launch_bounds__(384)
void attn_kernel(const ushort* __restrict__ q, const ushort* __restrict__ k,
                 const ushort* __restrict__ vt,
                 ushort* __restrict__ Ohi, ushort* __restrict__ Olo)
{
    const int g   = blockIdx.x;
    const int tid = threadIdx.x;
    __shared__ __align__(16) char lds[37888];

    {
        const ushort* Qg = q  + (size_t)g * GSZ;
        const ushort* Kg = k  + (size_t)g * GSZ;
        const ushort* Vg = vt + (size_t)g * GSZ;
        const int t  = tid >> 2, kg = tid & 3;
        uint4 aq = *(const uint4*)(Qg + tid * 8);
        *(uint4*)(lds + kg*1568 + t*16) = aq;
        uint4 ak = *(const uint4*)(Kg + tid * 8);
        *(uint4*)(lds + 6272 + kg*1568 + t*16) = ak;
        const int hd = tid / 12, pl = tid - hd*12;
        uint4 av = *(const uint4*)(Vg + tid * 8);
        *(uint4*)(lds + 12544 + pl*544 + hd*16) = av;
    }
    __syncthreads();

    const int w = tid >> 6, lane = tid & 63;
    const int lr = lane & 15, kgl = lane >> 4;

    f32x4 acc[6];
    {
        bf16x8 aq = *(const bf16x8*)(lds + kgl*1568 + (w*16 + lr)*16);
        #pragma unroll
        for (int n = 0; n < 6; n++) {
            bf16x8 bk = *(const bf16x8*)(lds + 6272 + kgl*1568 + (n*16 + lr)*16);
            acc[n] = __builtin_amdgcn_mfma_f32_16x16x32_bf16(aq, bk, (f32x4)0.f, 0, 0, 0);
        }
    }

    float mx[4], sm[4], inv[4];
    #pragma unroll
    for (int reg = 0; reg < 4; reg++) {
        float m = acc[0][reg];
        #pragma unroll
        for (int n = 1; n < 6; n++) m = fmaxf(m, acc[n][reg]);
        mx[reg] = m;
    }
    #pragma unroll
    for (int off = 1; off < 16; off <<= 1)
        #pragma unroll
        for (int reg = 0; reg < 4; reg++)
            mx[reg] = fmaxf(mx[reg], __shfl_xor(mx[reg], off));
    #pragma unroll
    for (int reg = 0; reg < 4; reg++) sm[reg] = 0.f;
    #pragma unroll
    for (int n = 0; n < 6; n++)
        #pragma unroll
        for (int reg = 0; reg < 4; reg++) {
            float e = __expf(acc[n][reg] - mx[reg]);
            acc[n][reg] = e;
            sm[reg] += e;
        }
    #pragma unroll
    for (int off = 1; off < 16; off <<= 1)
        #pragma unroll
        for (int reg = 0; reg < 4; reg++)
            sm[reg] += __shfl_xor(sm[reg], off);
    #pragma unroll
    for (int reg = 0; reg < 4; reg++) inv[reg] = 1.0f / sm[reg];

    #pragma unroll
    for (int n = 0; n < 6; n++) {
        const int pl = (n >> 1)*4 + ((n*2 + (lr >> 3)) & 3);
        const int j  = lr & 7;
        #pragma unroll
        for (int reg = 0; reg < 4; reg++) {
            const int row = w*16 + kgl*4 + reg;
            *(ushort*)(lds + 19072 + pl*1568 + row*16 + j*2) =
                to_bf16(acc[n][reg] * inv[reg]);
        }
    }
    __syncthreads();

    f32x4 o[2] = {(f32x4)0.f, (f32x4)0.f};
    #pragma unroll
    for (int ks = 0; ks < 3; ks++) {
        bf16x8 ap = *(const bf16x8*)(lds + 19072 + (ks*4 + kgl)*1568 + (w*16 + lr)*16);
        #pragma unroll
        for (int n2 = 0; n2 < 2; n2++) {
            bf16x8 bv = *(const bf16x8*)(lds + 12544 + (ks*4 + kgl)*544 + (n2*16 + lr)*16);
            o[n2] = __builtin_amdgcn_mfma_f32_16x16x32_bf16(ap, bv, o[n2], 0, 0, 0);
        }
    }

    // store O as bf16 hi/lo: row = bn*96 + qr, col = h*32 + n2*16 + lr
    const int bn = g >> 3, h = g & 7;
    const size_t rb = (size_t)(bn * T_) * D_ + h * HD_;
    #pragma unroll
    for (int n2 = 0; n2 < 2; n2++)
        #pragma unroll
        for (int reg = 0; reg < 4; reg++) {
            const int qr = w*16 + kgl*4 + reg;
            const size_t idx = rb + (size_t)qr * D_ + n2*16 + lr;
            float val = o[n2][reg];
            uint u = __builtin_bit_cast(uint, val);
            ushort hv = (ushort)(u >> 16);
            float hf = __builtin_bit_cast(float, u & 0xFFFF0000u);
            float lf = val - hf;
            ushort lv = (ushort)(__builtin_bit_cast(uint, lf) >> 16);
            Ohi[idx] = hv;
            Olo[idx] = lv;
        }
}

// ---------------------------------------------------------------------------
// Kernel 3: d_out = O @ Wo^T + bo.  All operands pre-split bf16 -> pure
// global_load_lds staging, zero VALU conversion.  BM=128, BN=256, BK=32,
// 512 thr = 8 waves (2x4), 64x64 per wave.
// ---------------------------------------------------------------------------
__global__ __launch_bounds__(512)
void wo_kernel(const ushort* __restrict__ Ohi, const ushort* __restrict__ Olo,
               const ushort* __restrict__ whi, const ushort* __restrict__ wlo,
               const float* __restrict__ bo, float* __restrict__ io)
{
    const int tid  = threadIdx.x;
    const int row0 = blockIdx.x * 128;
    const int lane = tid & 63;
    const int w    = tid >> 6;
    const int wr   = w >> 2;
    const int wc   = w & 3;
    const int lr   = lane & 15;
    const int kgl  = lane >> 4;
    const ushort* Wh = whi + (size_t)3 * WSZ;
    const ushort* Wl = wlo + (size_t)3 * WSZ;

    __shared__ __align__(16) ushort Ah[4*128*8];   // 8 KB
    __shared__ __align__(16) ushort Al[4*128*8];
    __shared__ __align__(16) ushort Bh[4*256*8];   // 16 KB
    __shared__ __align__(16) ushort Bl[4*256*8];

    f32x4 acc[4][4];
    #pragma unroll
    for (int m = 0; m < 4; m++)
        #pragma unroll
        for (int n = 0; n < 4; n++) acc[m][n] = (f32x4)0.f;

    for (int k0 = 0; k0 < D_; k0 += 32) {
        // A: 512 chunks (kg,r) over 8 waves; per-lane gather, linear LDS dest
        {
            const int c  = w*64 + lane;
            const int kg = c >> 7, r = c & 127;
            const size_t goff = (size_t)(row0 + r) * D_ + k0 + kg * 8;
            const uint off = (uint)__builtin_amdgcn_readfirstlane(w * 1024);
            async_load16(Ohi + goff, (char*)Ah + off);
            async_load16(Olo + goff, (char*)Al + off);
        }
        // B: 1024 chunks over 8 waves (2 issues each buf); contiguous runs
        {
            const int kg = w >> 1;
            const size_t gb = ((size_t)(k0/8 + kg) * 256 + (w & 1) * 128) * 8;
            const uint off = (uint)__builtin_amdgcn_readfirstlane(w * 2048);
            async_load16(Wh + gb + (size_t)lane * 8,        (char*)Bh + off);
            async_load16(Wh + gb + (size_t)(64 + lane) * 8, (char*)Bh + off + 1024);
            async_load16(Wl + gb + (size_t)lane * 8,        (char*)Bl + off);
            async_load16(Wl + gb + (size_t)(64 + lane) * 8, (char*)Bl + off + 1024);
        }
        __syncthreads();

        bf16x8 ah[4], al[4], bh[4], bl[4];
        #pragma unroll
        for (int m = 0; m < 4; m++) {
            const int ra = wr*64 + m*16 + lr;
            ah[m] = *(const bf16x8*)&Ah[(kgl*128 + ra)*8];
            al[m] = *(const bf16x8*)&Al[(kgl*128 + ra)*8];
        }
        #pragma unroll
        for (int n = 0; n < 4; n++) {
            const int cb = wc*64 + n*16 + lr;
            bh[n] = *(const bf16x8*)&Bh[(kgl*256 + cb)*8];
            bl[n] = *(const bf16x8*)&Bl[(kgl*256 + cb)*8];
        }
        #pragma unroll
        for (int m = 0; m < 4; m++)
            #pragma unroll
            for (int n = 0; n < 4; n++) {
                acc[m][n] = __builtin_amdgcn_mfma_f32_16x16x32_bf16(ah[m], bl[n], acc[m][n], 0, 0, 0);
                acc[m][n] = __builtin_amdgcn_mfma_f32_16x16x32_bf16(al[m], bh[n], acc[m][n], 0, 0, 0);
                acc[m][n] = __builtin_amdgcn_mfma_f32_16x16x32_bf16(ah[m], bh[n], acc[m][n], 0, 0, 0);
            }
        __syncthreads();
    }

    #pragma unroll
    for (int n = 0; n < 4; n++) {
        const int gcol = wc*64 + n*16 + lr;
        const float bv = bo[gcol];
        #pragma unroll
        for (int m = 0; m < 4; m++) {
            #pragma unroll
            for (int reg = 0; reg < 4; reg++) {
                const int grow = row0 + wr*64 + m*16 + kgl*4 + reg;
                io[(size_t)grow * D_ + gcol] = acc[m][n][reg] + bv;
            }
        }
    }
}

// ---------------------------------------------------------------------------
extern "C" void kernel_launch(void* const* d_in, const int* in_sizes, int n_in,
                              void* d_out, int out_size, void* d_ws, size_t ws_size,
                              hipStream_t stream)
{
    const float* query = (const float*)d_in[0];
    const float* key   = (const float*)d_in[1];
    const float* value = (const float*)d_in[2];
    // d_in[3..5]: pattern_matrix, Wp, bp -- mathematically a no-op (mask == 1)
    const float* Wq = (const float*)d_in[6];
    const float* bq = (const float*)d_in[7];
    const float* Wk = (const float*)d_in[8];
    const float* bk = (const float*)d_in[9];
    const float* Wv = (const float*)d_in[10];
    const float* bv = (const float*)d_in[11];
    const float* Wo = (const float*)d_in[12];
    const float* bo = (const float*)d_in[13];

    float*  out = (float*)d_out;
    ushort* ws  = (ushort*)d_ws;
    ushort* qb  = ws;                        // bf16 [g][t][hd], 1/sqrt(32) folded
    ushort* kb  = ws + (size_t)QSZ;          // bf16 [g][t][hd]
    ushort* vb  = ws + (size_t)QSZ * 2;      // bf16 [g][hd][t]
    ushort* ohi = ws + (size_t)QSZ * 3;      // attn out hi bf16 [row][col]
    ushort* olo = ws + (size_t)QSZ * 4;      // attn out lo
    ushort* whi = ws + (size_t)QSZ * 5;                    // 4 matrices chunked
    ushort* wlo = ws + (size_t)QSZ * 5 + (size_t)4 * WSZ;  // total ~168 MB

    splitw_kernel<<<dim3(128), 256, 0, stream>>>(Wq, Wk, Wv, Wo, whi, wlo);
    proj_kernel<<<dim3(2, R_ / 128, 3), 256, 0, stream>>>(
        query, key, value, whi, wlo, bq, bk, bv, qb, kb, vb);
    attn_kernel<<<dim3(G_), 384, 0, stream>>>(qb, kb, vb, ohi, olo);
    wo_kernel<<<dim3(R_ / 128), 512, 0, stream>>>(ohi, olo, whi, wlo, bo, out);
}

// Round 5
// 200.161 us; speedup vs baseline: 1.5458x; 1.5458x over previous
//
#include <hip/hip_runtime.h>
#include <math.h>

// Problem constants
#define B_  4
#define N_  170
#define T_  96
#define D_  256
#define H_  8
#define HD_ 32
#define R_  (B_*N_*T_)    // 65280 rows
#define G_  (B_*N_*H_)    // 5440 attention groups
#define GSZ (T_*HD_)      // 3072 elements per group per tensor
#define QSZ (R_*D_)       // 16,711,680 elements per q/k/v buffer (bf16)
#define WSZ (D_*D_)       // 65536 per weight matrix

typedef short  bf16x8 __attribute__((ext_vector_type(8)));
typedef float  f32x4  __attribute__((ext_vector_type(4)));
typedef unsigned int u32;

__device__ __forceinline__ ushort to_bf16(float x)
{
    uint u = __builtin_bit_cast(uint, x);
    u += 0x8000u;                      // round-half-up
    return (ushort)(u >> 16);
}

__device__ __forceinline__ uint pack2(float x0, float x1)
{
    return (uint)to_bf16(x0) | ((uint)to_bf16(x1) << 16);
}

__device__ __forceinline__ uint4 pack8(float4 a0, float4 a1)
{
    uint4 r;
    r.x = pack2(a0.x, a0.y); r.y = pack2(a0.z, a0.w);
    r.z = pack2(a1.x, a1.y); r.w = pack2(a1.z, a1.w);
    return r;
}

// split fp32 pair into packed bf16 hi (truncate; x-hi exact) and lo words
__device__ __forceinline__ void split2(float x0, float x1, uint& hi, uint& lo)
{
    uint u0 = __builtin_bit_cast(uint, x0);
    uint u1 = __builtin_bit_cast(uint, x1);
    hi = (u0 >> 16) | (u1 & 0xFFFF0000u);
    float h0 = __builtin_bit_cast(float, u0 & 0xFFFF0000u);
    float h1 = __builtin_bit_cast(float, u1 & 0xFFFF0000u);
    float l0 = x0 - h0, l1 = x1 - h1;
    uint v0 = __builtin_bit_cast(uint, l0);
    uint v1 = __builtin_bit_cast(uint, l1);
    lo = (v0 >> 16) | (v1 & 0xFFFF0000u);
}

__device__ __forceinline__ void split8(float4 a0, float4 a1, uint4& hi, uint4& lo)
{
    split2(a0.x, a0.y, hi.x, lo.x);
    split2(a0.z, a0.w, hi.y, lo.y);
    split2(a1.x, a1.y, hi.z, lo.z);
    split2(a1.z, a1.w, hi.w, lo.w);
}

// async global->LDS, 16B per lane; lds dest = wave-uniform base + lane*16 (HW)
__device__ __forceinline__ void async_load16(const void* g, void* l)
{
    __builtin_amdgcn_global_load_lds(
        (const u32 __attribute__((address_space(1)))*)g,
        (u32 __attribute__((address_space(3)))*)l,
        16, 0, 0);
}

// ---------------------------------------------------------------------------
// Kernel 0: one-time W split. W[col][k] fp32 -> hi/lo bf16 in chunked layout
// [k/8][col][8] per matrix.  Wq gets 1/sqrt(32) folded in. 0=Wq 1=Wk 2=Wv 3=Wo.
// ---------------------------------------------------------------------------
__global__ __launch_bounds__(256)
void splitw_kernel(const float* __restrict__ Wq, const float* __restrict__ Wk,
                   const float* __restrict__ Wv, const float* __restrict__ Wo,
                   ushort* __restrict__ whi, ushort* __restrict__ wlo)
{
    const int gid = blockIdx.x * 256 + threadIdx.x;   // 32768 chunks
    const int mat = gid >> 13;
    const int rem = gid & 8191;
    const int col = rem >> 5;
    const int kc  = rem & 31;
    const float* W = (mat == 0) ? Wq : (mat == 1) ? Wk : (mat == 2) ? Wv : Wo;
    const float s  = (mat == 0) ? 0.17677669529663687f : 1.0f;
    const float* p = W + (size_t)col * D_ + kc * 8;
    float4 a0 = *(const float4*)p;
    float4 a1 = *(const float4*)(p + 4);
    a0.x *= s; a0.y *= s; a0.z *= s; a0.w *= s;
    a1.x *= s; a1.y *= s; a1.z *= s; a1.w *= s;
    uint4 h, l;
    split8(a0, a1, h, l);
    const size_t off = (size_t)mat * WSZ + ((size_t)kc * 256 + col) * 8;
    *(uint4*)(whi + off) = h;
    *(uint4*)(wlo + off) = l;
}

// ---------------------------------------------------------------------------
// Kernel 1: fused Q/K/V projection. A = X rounded to bf16 (reg-staged, cvt in
// kernel); B = pre-split W hi/lo via global_load_lds. 2-phase double-buffered
// K-loop: stage t+1 first, compute t, ONE __syncthreads per step -> loads fly
// under the 32 MFMAs. BM=128, BN=128, BK=32, 256 thr = 4 waves, 64x64/wave.
// LDS plane pad 130 chunks (2080B = +8 banks) -> conflict-free frag reads.
// ---------------------------------------------------------------------------
__global__ __launch_bounds__(256)
void proj_kernel(const float* __restrict__ Xq, const float* __restrict__ Xk,
                 const float* __restrict__ Xv,
                 const ushort* __restrict__ whi, const ushort* __restrict__ wlo,
                 const float* __restrict__ bq, const float* __restrict__ bk,
                 const float* __restrict__ bv,
                 ushort* __restrict__ oq, ushort* __restrict__ ok_,
                 ushort* __restrict__ ov)
{
    const int z = blockIdx.z;
    const float* X    = (z == 0) ? Xq : (z == 1) ? Xk : Xv;
    const float* bias = (z == 0) ? bq : (z == 1) ? bk : bv;
    ushort*      out  = (z == 0) ? oq : (z == 1) ? ok_ : ov;
    const ushort* Wh = whi + (size_t)z * WSZ;
    const ushort* Wl = wlo + (size_t)z * WSZ;

    const int tid  = threadIdx.x;
    const int lane = tid & 63;
    const int w    = tid >> 6;
    const int col0 = blockIdx.x * 128;
    const int row0 = blockIdx.y * 128;
    const int wr   = w >> 1;
    const int wc   = w & 1;
    const int lr   = lane & 15;
    const int kgl  = lane >> 4;

    __shared__ __align__(16) char Alds[2][8320];    // 4 planes x 130 chunks
    __shared__ __align__(16) char Blds[2][16640];   // 8 planes (hi:0-3, lo:4-7)

    // A stage descriptors: 2 chunks/thread (chunk = 8 bf16 = 16B)
    const int cA1 = tid + 256;
    const int kA0 = tid >> 7, rA0 = tid & 127;
    const int kA1 = cA1 >> 7, rA1 = cA1 & 127;
    const float* pa0 = X + (size_t)(row0 + rA0) * D_ + kA0 * 8;
    const float* pa1 = X + (size_t)(row0 + rA1) * D_ + kA1 * 8;
    const uint wa0 = (uint)(kA0 * 130 + rA0) * 16;
    const uint wa1 = (uint)(kA1 * 130 + rA1) * 16;

    // B stage descriptors: 4 gl_lds issues/wave (64-chunk linear segments)
    const ushort* pb[4];
    uint wb[4];
    #pragma unroll
    for (int i = 0; i < 4; i++) {
        const int s = w * 4 + i, hl = s >> 3, kg = (s >> 1) & 3, colh = s & 1;
        pb[i] = (hl ? Wl : Wh) + ((size_t)kg * 256 + col0 + colh * 64 + lane) * 8;
        wb[i] = (uint)__builtin_amdgcn_readfirstlane(
                    (((hl * 4 + kg) * 130) + colh * 64) * 16);
    }

    f32x4 acc[4][4];
    #pragma unroll
    for (int m = 0; m < 4; m++)
        #pragma unroll
        for (int n = 0; n < 4; n++) acc[m][n] = (f32x4)0.f;

    float4 a00, a01, a10, a11;   // in-flight A regs (16 VGPR)

    // prologue: stage tile 0 into buf 0
    #pragma unroll
    for (int i = 0; i < 4; i++) async_load16(pb[i], Blds[0] + wb[i]);
    a00 = *(const float4*)pa0; a01 = *(const float4*)(pa0 + 4);
    a10 = *(const float4*)pa1; a11 = *(const float4*)(pa1 + 4);
    *(uint4*)(Alds[0] + wa0) = pack8(a00, a01);
    *(uint4*)(Alds[0] + wa1) = pack8(a10, a11);
    __syncthreads();

    for (int t = 0; t < 8; t++) {
        const int cur = t & 1, nxt = cur ^ 1;
        if (t < 7) {   // issue next-tile stages FIRST (fly under compute)
            #pragma unroll
            for (int i = 0; i < 4; i++)
                async_load16(pb[i] + (size_t)(t + 1) * 8192, Blds[nxt] + wb[i]);
            const float* q0 = pa0 + (t + 1) * 32;
            const float* q1 = pa1 + (t + 1) * 32;
            a00 = *(const float4*)q0; a01 = *(const float4*)(q0 + 4);
            a10 = *(const float4*)q1; a11 = *(const float4*)(q1 + 4);
        }
        // compute current tile
        bf16x8 a[4];
        #pragma unroll
        for (int m = 0; m < 4; m++)
            a[m] = *(const bf16x8*)(Alds[cur] + (kgl*130 + wr*64 + m*16 + lr) * 16);
        #pragma unroll
        for (int n = 0; n < 4; n++) {
            const int cb = wc*64 + n*16 + lr;
            bf16x8 bh = *(const bf16x8*)(Blds[cur] + (kgl*130 + cb) * 16);
            bf16x8 bl = *(const bf16x8*)(Blds[cur] + ((4 + kgl)*130 + cb) * 16);
            #pragma unroll
            for (int m = 0; m < 4; m++) {
                acc[m][n] = __builtin_amdgcn_mfma_f32_16x16x32_bf16(a[m], bl, acc[m][n], 0, 0, 0);
                acc[m][n] = __builtin_amdgcn_mfma_f32_16x16x32_bf16(a[m], bh, acc[m][n], 0, 0, 0);
            }
        }
        if (t < 7) {   // write staged A into next buffer (after compute)
            *(uint4*)(Alds[nxt] + wa0) = pack8(a00, a01);
            *(uint4*)(Alds[nxt] + wa1) = pack8(a10, a11);
        }
        __syncthreads();
    }

    // epilogue: + bias -> bf16, head-split store (Wq pre-scaled; bias scaled here)
    const float sc = (z == 0) ? 0.17677669529663687f : 1.0f;
    if (z < 2) {
        #pragma unroll
        for (int n = 0; n < 4; n++) {
            const int gcol = col0 + wc*64 + n*16 + lr;
            const int h    = gcol >> 5;
            const int hd   = gcol & 31;
            const float bvs = bias[gcol] * sc;
            #pragma unroll
            for (int m = 0; m < 4; m++) {
                #pragma unroll
                for (int reg = 0; reg < 4; reg++) {
                    const int grow = row0 + wr*64 + m*16 + kgl*4 + reg;
                    const int bn = grow / T_;
                    const int t  = grow - bn * T_;
                    out[(size_t)((bn*H_ + h)*T_ + t)*HD_ + hd] = to_bf16(acc[m][n][reg] + bvs);
                }
            }
        }
    } else {
        // v: [g][hd][t], pack 4 consecutive t (reg dim) into ushort4
        #pragma unroll
        for (int n = 0; n < 4; n++) {
            const int gcol = col0 + wc*64 + n*16 + lr;
            const int h    = gcol >> 5;
            const int hd   = gcol & 31;
            const float bvs = bias[gcol];
            #pragma unroll
            for (int m = 0; m < 4; m++) {
                const int grow0 = row0 + wr*64 + m*16 + kgl*4;  // 4 | 96 -> one bn
                const int bn = grow0 / T_;
                const int t0 = grow0 - bn * T_;
                ushort4 pk;
                pk.x = to_bf16(acc[m][n][0] + bvs);
                pk.y = to_bf16(acc[m][n][1] + bvs);
                pk.z = to_bf16(acc[m][n][2] + bvs);
                pk.w = to_bf16(acc[m][n][3] + bvs);
                *(ushort4*)&out[(size_t)((bn*H_ + h)*HD_ + hd)*T_ + t0] = pk;
            }
        }
    }
}

// ---------------------------------------------------------------------------
// Kernel 2: MFMA attention, one block per (bn,h), 384 thr = 6 waves.
// O written as SINGLE bf16 row-major [bn*96+t][h*32+hd] for wo_kernel.
// ---------------------------------------------------------------------------
__global__ __launch_bounds__(384)
void attn_kernel(const ushort* __restrict__ q, const ushort* __restrict__ k,
                 const ushort* __restrict__ vt, ushort* __restrict__ Obf)
{
    const int g   = blockIdx.x;
    const int tid = threadIdx.x;
    __shared__ __align__(16) char lds[37888];

    {
        const ushort* Qg = q  + (size_t)g * GSZ;
        const ushort* Kg = k  + (size_t)g * GSZ;
        const ushort* Vg = vt + (size_t)g * GSZ;
        const int t  = tid >> 2, kg = tid & 3;
        uint4 aq = *(const uint4*)(Qg + tid * 8);
        *(uint4*)(lds + kg*1568 + t*16) = aq;
        uint4 ak = *(const uint4*)(Kg + tid * 8);
        *(uint4*)(lds + 6272 + kg*1568 + t*16) = ak;
        const int hd = tid / 12, pl = tid - hd*12;
        uint4 av = *(const uint4*)(Vg + tid * 8);
        *(uint4*)(lds + 12544 + pl*544 + hd*16) = av;
    }
    __syncthreads();

    const int w = tid >> 6, lane = tid & 63;
    const int lr = lane & 15, kgl = lane >> 4;

    f32x4 acc[6];
    {
        bf16x8 aq = *(const bf16x8*)(lds + kgl*1568 + (w*16 + lr)*16);
        #pragma unroll
        for (int n = 0; n < 6; n++) {
            bf16x8 bk = *(const bf16x8*)(lds + 6272 + kgl*1568 + (n*16 + lr)*16);
            acc[n] = __builtin_amdgcn_mfma_f32_16x16x32_bf16(aq, bk, (f32x4)0.f, 0, 0, 0);
        }
    }

    float mx[4], sm[4], inv[4];
    #pragma unroll
    for (int reg = 0; reg < 4; reg++) {
        float m = acc[0][reg];
        #pragma unroll
        for (int n = 1; n < 6; n++) m = fmaxf(m, acc[n][reg]);
        mx[reg] = m;
    }
    #pragma unroll
    for (int off = 1; off < 16; off <<= 1)
        #pragma unroll
        for (int reg = 0; reg < 4; reg++)
            mx[reg] = fmaxf(mx[reg], __shfl_xor(mx[reg], off));
    #pragma unroll
    for (int reg = 0; reg < 4; reg++) sm[reg] = 0.f;
    #pragma unroll
    for (int n = 0; n < 6; n++)
        #pragma unroll
        for (int reg = 0; reg < 4; reg++) {
            float e = __expf(acc[n][reg] - mx[reg]);
            acc[n][reg] = e;
            sm[reg] += e;
        }
    #pragma unroll
    for (int off = 1; off < 16; off <<= 1)
        #pragma unroll
        for (int reg = 0; reg < 4; reg++)
            sm[reg] += __shfl_xor(sm[reg], off);
    #pragma unroll
    for (int reg = 0; reg < 4; reg++) inv[reg] = 1.0f / sm[reg];

    #pragma unroll
    for (int n = 0; n < 6; n++) {
        const int pl = (n >> 1)*4 + ((n*2 + (lr >> 3)) & 3);
        const int j  = lr & 7;
        #pragma unroll
        for (int reg = 0; reg < 4; reg++) {
            const int row = w*16 + kgl*4 + reg;
            *(ushort*)(lds + 19072 + pl*1568 + row*16 + j*2) =
                to_bf16(acc[n][reg] * inv[reg]);
        }
    }
    __syncthreads();

    f32x4 o[2] = {(f32x4)0.f, (f32x4)0.f};
    #pragma unroll
    for (int ks = 0; ks < 3; ks++) {
        bf16x8 ap = *(const bf16x8*)(lds + 19072 + (ks*4 + kgl)*1568 + (w*16 + lr)*16);
        #pragma unroll
        for (int n2 = 0; n2 < 2; n2++) {
            bf16x8 bv = *(const bf16x8*)(lds + 12544 + (ks*4 + kgl)*544 + (n2*16 + lr)*16);
            o[n2] = __builtin_amdgcn_mfma_f32_16x16x32_bf16(ap, bv, o[n2], 0, 0, 0);
        }
    }

    const int bn = g >> 3, h = g & 7;
    const size_t rb = (size_t)(bn * T_) * D_ + h * HD_;
    #pragma unroll
    for (int n2 = 0; n2 < 2; n2++)
        #pragma unroll
        for (int reg = 0; reg < 4; reg++) {
            const int qr = w*16 + kgl*4 + reg;
            Obf[rb + (size_t)qr * D_ + n2*16 + lr] = to_bf16(o[n2][reg]);
        }
}

// ---------------------------------------------------------------------------
// Kernel 3: d_out = O @ Wo^T + bo. A (O bf16) and B (Wo hi/lo) both via
// global_load_lds, same 2-phase double-buffered loop as proj.
// BM=128, BN=128, BK=32, 256 thr = 4 waves.
// ---------------------------------------------------------------------------
__global__ __launch_bounds__(256)
void wo_kernel(const ushort* __restrict__ Obf,
               const ushort* __restrict__ whi, const ushort* __restrict__ wlo,
               const float* __restrict__ bo, float* __restrict__ io)
{
    const int tid  = threadIdx.x;
    const int lane = tid & 63;
    const int w    = tid >> 6;
    const int col0 = blockIdx.x * 128;
    const int row0 = blockIdx.y * 128;
    const int wr   = w >> 1;
    const int wc   = w & 1;
    const int lr   = lane & 15;
    const int kgl  = lane >> 4;
    const ushort* Wh = whi + (size_t)3 * WSZ;
    const ushort* Wl = wlo + (size_t)3 * WSZ;

    __shared__ __align__(16) char Alds[2][8320];
    __shared__ __align__(16) char Blds[2][16640];

    // A: 2 gl_lds issues/wave (s = w*2+i: kg = s>>1, rhalf = s&1)
    const ushort* pa[2];
    uint wa[2];
    #pragma unroll
    for (int i = 0; i < 2; i++) {
        const int s = w * 2 + i, kg = s >> 1, rhalf = s & 1;
        pa[i] = Obf + (size_t)(row0 + rhalf * 64 + lane) * D_ + kg * 8;
        wa[i] = (uint)__builtin_amdgcn_readfirstlane((kg * 130 + rhalf * 64) * 16);
    }
    // B: 4 gl_lds issues/wave
    const ushort* pb[4];
    uint wb[4];
    #pragma unroll
    for (int i = 0; i < 4; i++) {
        const int s = w * 4 + i, hl = s >> 3, kg = (s >> 1) & 3, colh = s & 1;
        pb[i] = (hl ? Wl : Wh) + ((size_t)kg * 256 + col0 + colh * 64 + lane) * 8;
        wb[i] = (uint)__builtin_amdgcn_readfirstlane(
                    (((hl * 4 + kg) * 130) + colh * 64) * 16);
    }

    f32x4 acc[4][4];
    #pragma unroll
    for (int m = 0; m < 4; m++)
        #pragma unroll
        for (int n = 0; n < 4; n++) acc[m][n] = (f32x4)0.f;

    // prologue
    #pragma unroll
    for (int i = 0; i < 2; i++) async_load16(pa[i], Alds[0] + wa[i]);
    #pragma unroll
    for (int i = 0; i < 4; i++) async_load16(pb[i], Blds[0] + wb[i]);
    __syncthreads();

    for (int t = 0; t < 8; t++) {
        const int cur = t & 1, nxt = cur ^ 1;
        if (t < 7) {
            #pragma unroll
            for (int i = 0; i < 2; i++)
                async_load16(pa[i] + (size_t)(t + 1) * 32, Alds[nxt] + wa[i]);
            #pragma unroll
            for (int i = 0; i < 4; i++)
                async_load16(pb[i] + (size_t)(t + 1) * 8192, Blds[nxt] + wb[i]);
        }
        bf16x8 a[4];
        #pragma unroll
        for (int m = 0; m < 4; m++)
            a[m] = *(const bf16x8*)(Alds[cur] + (kgl*130 + wr*64 + m*16 + lr) * 16);
        #pragma unroll
        for (int n = 0; n < 4; n++) {
            const int cb = wc*64 + n*16 + lr;
            bf16x8 bh = *(const bf16x8*)(Blds[cur] + (kgl*130 + cb) * 16);
            bf16x8 bl = *(const bf16x8*)(Blds[cur] + ((4 + kgl)*130 + cb) * 16);
            #pragma unroll
            for (int m = 0; m < 4; m++) {
                acc[m][n] = __builtin_amdgcn_mfma_f32_16x16x32_bf16(a[m], bl, acc[m][n], 0, 0, 0);
                acc[m][n] = __builtin_amdgcn_mfma_f32_16x16x32_bf16(a[m], bh, acc[m][n], 0, 0, 0);
            }
        }
        __syncthreads();
    }

    #pragma unroll
    for (int n = 0; n < 4; n++) {
        const int gcol = col0 + wc*64 + n*16 + lr;
        const float bv = bo[gcol];
        #pragma unroll
        for (int m = 0; m < 4; m++) {
            #pragma unroll
            for (int reg = 0; reg < 4; reg++) {
                const int grow = row0 + wr*64 + m*16 + kgl*4 + reg;
                io[(size_t)grow * D_ + gcol] = acc[m][n][reg] + bv;
            }
        }
    }
}

// ---------------------------------------------------------------------------
extern "C" void kernel_launch(void* const* d_in, const int* in_sizes, int n_in,
                              void* d_out, int out_size, void* d_ws, size_t ws_size,
                              hipStream_t stream)
{
    const float* query = (const float*)d_in[0];
    const float* key   = (const float*)d_in[1];
    const float* value = (const float*)d_in[2];
    // d_in[3..5]: pattern_matrix, Wp, bp -- mathematically a no-op (mask == 1)
    const float* Wq = (const float*)d_in[6];
    const float* bq = (const float*)d_in[7];
    const float* Wk = (const float*)d_in[8];
    const float* bk = (const float*)d_in[9];
    const float* Wv = (const float*)d_in[10];
    const float* bv = (const float*)d_in[11];
    const float* Wo = (const float*)d_in[12];
    const float* bo = (const float*)d_in[13];

    float*  out = (float*)d_out;
    ushort* ws  = (ushort*)d_ws;
    ushort* qb  = ws;                        // bf16 [g][t][hd], 1/sqrt(32) folded
    ushort* kb  = ws + (size_t)QSZ;          // bf16 [g][t][hd]
    ushort* vb  = ws + (size_t)QSZ * 2;      // bf16 [g][hd][t]
    ushort* ob  = ws + (size_t)QSZ * 3;      // attn out bf16 [row][col]
    ushort* whi = ws + (size_t)QSZ * 4;                    // 4 matrices chunked
    ushort* wlo = ws + (size_t)QSZ * 4 + (size_t)4 * WSZ;  // total ~135 MB

    splitw_kernel<<<dim3(128), 256, 0, stream>>>(Wq, Wk, Wv, Wo, whi, wlo);
    proj_kernel<<<dim3(2, R_ / 128, 3), 256, 0, stream>>>(
        query, key, value, whi, wlo, bq, bk, bv, qb, kb, vb);
    attn_kernel<<<dim3(G_), 384, 0, stream>>>(qb, kb, vb, ob);
    wo_kernel<<<dim3(2, R_ / 128), 256, 0, stream>>>(ob, whi, wlo, bo, out);
}